// Round 2
// baseline (651.677 us; speedup 1.0000x reference)
//
#include <hip/hip_runtime.h>
#include <stdint.h>
#include <math.h>

#define NB   16384   // batch
#define DIN  2000
#define NH   500     // hidden
#define ND   64      // dim
#define NKC  256     // clusters

#define FLAG_CAP 4096
#define GAP_THR  0.08f   // in sum-of-squares units (mean-units * 64); noise ~9e-4

typedef __attribute__((ext_vector_type(4))) float  f32x4;
typedef __attribute__((ext_vector_type(8))) short  s16x8;

// ---------- bf16 helpers ----------
__device__ __forceinline__ unsigned short f2bf_rne(float v) {
  unsigned int u = __float_as_uint(v);
  u += 0x7fffu + ((u >> 16) & 1u);
  return (unsigned short)(u >> 16);
}
// fast split: hi = truncate-to-bf16, lo = truncate(v - hi). total rel err <= 2^-16
__device__ __forceinline__ void split_rtz(float v, unsigned short &hi, unsigned short &lo) {
  unsigned int u = __float_as_uint(v);
  hi = (unsigned short)(u >> 16);
  float r = v - __uint_as_float(u & 0xffff0000u);
  lo = (unsigned short)(__float_as_uint(r) >> 16);
}

// ---------- weight convert (+zero-pad) ----------
__global__ void k_split_pad(const float* __restrict__ in, unsigned short* __restrict__ hi,
                            unsigned short* __restrict__ lo,
                            int R, int C, int Cp, int total) {
  int stride = gridDim.x * blockDim.x;
  for (int idx = blockIdx.x * blockDim.x + threadIdx.x; idx < total; idx += stride) {
    int r = idx / Cp, c = idx - r * Cp;
    float v = (r < R && c < C) ? in[(size_t)r * C + c] : 0.f;
    if (lo) {
      unsigned short h, l; split_rtz(v, h, l);
      hi[idx] = h; lo[idx] = l;
    } else {
      hi[idx] = f2bf_rne(v);
    }
  }
}

// ---------- GEMM: C[M,N] = A[M,K] * B[N,K]^T (+bias, epilogue) ----------
// EPI: 0 = f32 store (col<store_n), 1 = relu + split bf16 (out0=hi,out1=lo),
//      2 = relu + bf16 store, 3 = sigmoid + f32 store (col<store_n)
template<int BN, int WC, bool SPLIT, bool AF32, int EPI>
__global__ __launch_bounds__(256) void k_gemm(
    const void* __restrict__ Ahi_, const void* __restrict__ Alo_,
    const unsigned short* __restrict__ Bhi, const unsigned short* __restrict__ Blo,
    const float* __restrict__ bias, int bias_n,
    void* __restrict__ out0, void* __restrict__ out1,
    int ldA, int K, int Kreal, int out_ld, int store_n)
{
  constexpr int BM = 128, BK = 32, LDK = BK + 8, WR = 4;
  __shared__ unsigned short aHi[BM * LDK];
  __shared__ unsigned short aLo[SPLIT ? BM * LDK : 1];
  __shared__ unsigned short bHi[BN * LDK];
  __shared__ unsigned short bLo[SPLIT ? BN * LDK : 1];

  const int tid  = threadIdx.x;
  const int lane = tid & 63, wave = tid >> 6;
  const int wm = wave >> 1, wn = wave & 1;
  const int lr = lane & 15, lg = lane >> 4;
  const int m0 = blockIdx.x * BM, n0 = blockIdx.y * BN;

  f32x4 acc[WR][WC];
#pragma unroll
  for (int i = 0; i < WR; ++i)
#pragma unroll
    for (int j = 0; j < WC; ++j)
#pragma unroll
      for (int r = 0; r < 4; ++r) acc[i][j][r] = 0.f;

  for (int k0 = 0; k0 < K; k0 += BK) {
    // ---- stage A ----
    if constexpr (AF32) {
      const float* A = (const float*)Ahi_;
#pragma unroll
      for (int it = 0; it < (BM * BK / 8) / 256; ++it) {
        int c = it * 256 + tid;
        int row = c >> 2;
        int kc = (c & 3) << 3;
        float vb[8];
        if (k0 + kc < Kreal) {   // chunks of 8; Kreal % 8 == 0
          const float* src = A + (size_t)(m0 + row) * ldA + (k0 + kc);
          f32x4 v0 = *(const f32x4*)src;
          f32x4 v1 = *(const f32x4*)(src + 4);
          vb[0] = v0[0]; vb[1] = v0[1]; vb[2] = v0[2]; vb[3] = v0[3];
          vb[4] = v1[0]; vb[5] = v1[1]; vb[6] = v1[2]; vb[7] = v1[3];
        } else {
#pragma unroll
          for (int j = 0; j < 8; ++j) vb[j] = 0.f;
        }
        s16x8 h8, l8;
#pragma unroll
        for (int j = 0; j < 8; ++j) {
          unsigned short h, l; split_rtz(vb[j], h, l);
          h8[j] = (short)h; l8[j] = (short)l;
        }
        *(s16x8*)&aHi[row * LDK + kc] = h8;
        *(s16x8*)&aLo[row * LDK + kc] = l8;
      }
    } else {
      const unsigned short* A = (const unsigned short*)Ahi_;
#pragma unroll
      for (int it = 0; it < (BM * BK / 8) / 256; ++it) {
        int c = it * 256 + tid;
        int row = c >> 2, kc = (c & 3) << 3;
        *(s16x8*)&aHi[row * LDK + kc] = *(const s16x8*)(A + (size_t)(m0 + row) * ldA + k0 + kc);
        if constexpr (SPLIT) {
          const unsigned short* AL = (const unsigned short*)Alo_;
          *(s16x8*)&aLo[row * LDK + kc] = *(const s16x8*)(AL + (size_t)(m0 + row) * ldA + k0 + kc);
        }
      }
    }
    // ---- stage B (pre-padded buffers, row stride = K) ----
#pragma unroll
    for (int it = 0; it < (BN * BK / 8) / 256; ++it) {
      int c = it * 256 + tid;
      int row = c >> 2, kc = (c & 3) << 3;
      *(s16x8*)&bHi[row * LDK + kc] = *(const s16x8*)(Bhi + (size_t)(n0 + row) * K + k0 + kc);
      if constexpr (SPLIT)
        *(s16x8*)&bLo[row * LDK + kc] = *(const s16x8*)(Blo + (size_t)(n0 + row) * K + k0 + kc);
    }
    __syncthreads();

    // ---- fragments + MFMA ----
    s16x8 ah[WR], bh[WC];
#pragma unroll
    for (int i = 0; i < WR; ++i)
      ah[i] = *(const s16x8*)&aHi[(wm * (WR * 16) + i * 16 + lr) * LDK + lg * 8];
#pragma unroll
    for (int j = 0; j < WC; ++j)
      bh[j] = *(const s16x8*)&bHi[(wn * (WC * 16) + j * 16 + lr) * LDK + lg * 8];
    if constexpr (SPLIT) {
      s16x8 al[WR], bl[WC];
#pragma unroll
      for (int i = 0; i < WR; ++i)
        al[i] = *(const s16x8*)&aLo[(wm * (WR * 16) + i * 16 + lr) * LDK + lg * 8];
#pragma unroll
      for (int j = 0; j < WC; ++j)
        bl[j] = *(const s16x8*)&bLo[(wn * (WC * 16) + j * 16 + lr) * LDK + lg * 8];
#pragma unroll
      for (int i = 0; i < WR; ++i)
#pragma unroll
        for (int j = 0; j < WC; ++j) {
          acc[i][j] = __builtin_amdgcn_mfma_f32_16x16x32_bf16(ah[i], bh[j], acc[i][j], 0, 0, 0);
          acc[i][j] = __builtin_amdgcn_mfma_f32_16x16x32_bf16(ah[i], bl[j], acc[i][j], 0, 0, 0);
          acc[i][j] = __builtin_amdgcn_mfma_f32_16x16x32_bf16(al[i], bh[j], acc[i][j], 0, 0, 0);
        }
    } else {
#pragma unroll
      for (int i = 0; i < WR; ++i)
#pragma unroll
        for (int j = 0; j < WC; ++j)
          acc[i][j] = __builtin_amdgcn_mfma_f32_16x16x32_bf16(ah[i], bh[j], acc[i][j], 0, 0, 0);
    }
    __syncthreads();
  }

  // ---- epilogue: C/D layout col=lane&15, row=(lane>>4)*4+reg ----
#pragma unroll
  for (int i = 0; i < WR; ++i) {
    int grow = m0 + wm * (WR * 16) + i * 16 + lg * 4;
#pragma unroll
    for (int j = 0; j < WC; ++j) {
      int gcol = n0 + wn * (WC * 16) + j * 16 + lr;
      float bv = (gcol < bias_n) ? bias[gcol] : 0.f;
      f32x4 v = acc[i][j];
#pragma unroll
      for (int r = 0; r < 4; ++r) {
        float val = v[r] + bv;
        int rr = grow + r;
        if constexpr (EPI == 0) {
          if (gcol < store_n) ((float*)out0)[(size_t)rr * out_ld + gcol] = val;
        } else if constexpr (EPI == 1) {
          val = fmaxf(val, 0.f);
          unsigned short h, l; split_rtz(val, h, l);
          ((unsigned short*)out0)[(size_t)rr * out_ld + gcol] = h;
          ((unsigned short*)out1)[(size_t)rr * out_ld + gcol] = l;
        } else if constexpr (EPI == 2) {
          val = fmaxf(val, 0.f);
          ((unsigned short*)out0)[(size_t)rr * out_ld + gcol] = f2bf_rne(val);
        } else {
          val = 1.f / (1.f + expf(-val));
          if (gcol < store_n) ((float*)out0)[(size_t)rr * out_ld + gcol] = val;
        }
      }
    }
  }
}

// ---------- zero the flag counter ----------
__global__ void k_zero(int* __restrict__ p) { if (threadIdx.x == 0) *p = 0; }

// ---------- clustering: dists, softmax(gamma), argmin -> quantized, flag close rows ----------
__global__ __launch_bounds__(256) void k_cluster(const float* __restrict__ z,
                                                 const float* __restrict__ mu,
                                                 float* __restrict__ gamma,
                                                 float* __restrict__ quant,
                                                 int* __restrict__ flag_cnt,
                                                 int* __restrict__ flag_list)
{
  __shared__ float mu_t[ND][NKC];   // 64 x 256 f32 = 64 KB, transposed for conflict-free reads
  for (int i = threadIdx.x; i < NKC * ND; i += 256) {
    int k = i >> 6, d = i & 63;
    mu_t[d][k] = mu[i];
  }
  __syncthreads();
  const int lane = threadIdx.x & 63, wave = threadIdx.x >> 6;
  for (int r4 = blockIdx.x * 16 + wave * 4; r4 < NB; r4 += gridDim.x * 16) {
    float zr[4];
#pragma unroll
    for (int r = 0; r < 4; ++r) zr[r] = z[(size_t)(r4 + r) * ND + lane];
    float ds[4][4];
#pragma unroll
    for (int r = 0; r < 4; ++r)
#pragma unroll
      for (int g = 0; g < 4; ++g) ds[r][g] = 0.f;
    for (int d = 0; d < ND; ++d) {
      f32x4 m4 = *(const f32x4*)&mu_t[d][lane << 2];   // this lane's 4 centroids
#pragma unroll
      for (int r = 0; r < 4; ++r) {
        float zd = __shfl(zr[r], d, 64);
#pragma unroll
        for (int g = 0; g < 4; ++g) {
          float t = zd - m4[g];
          ds[r][g] = fmaf(t, t, ds[r][g]);
        }
      }
    }
#pragma unroll
    for (int r = 0; r < 4; ++r) {
      int row = r4 + r;
      float bd = ds[r][0]; int bk = (lane << 2);
#pragma unroll
      for (int g = 1; g < 4; ++g)
        if (ds[r][g] < bd) { bd = ds[r][g]; bk = (lane << 2) + g; }
      for (int off = 1; off < 64; off <<= 1) {
        float od = __shfl_xor(bd, off, 64);
        int   ok = __shfl_xor(bk, off, 64);
        if (od < bd || (od == bd && ok < bk)) { bd = od; bk = ok; }  // first-index tie-break
      }
      // second-best (excluding global best index) for the flip-risk flag
      float sb = 3.4e38f;
#pragma unroll
      for (int g = 0; g < 4; ++g) {
        int kk = (lane << 2) + g;
        if (kk != bk) sb = fminf(sb, ds[r][g]);
      }
      for (int off = 1; off < 64; off <<= 1) sb = fminf(sb, __shfl_xor(sb, off, 64));
      if (lane == 0 && (sb - bd) < GAP_THR) {
        int p = atomicAdd(flag_cnt, 1);
        if (p < FLAG_CAP) flag_list[p] = row;
      }
      const float cc = -5.f / 64.f;   // DELTA / dim (z_dist is a mean)
      float e[4], s = 0.f;
#pragma unroll
      for (int g = 0; g < 4; ++g) { e[g] = expf(cc * (ds[r][g] - bd)); s += e[g]; }
      for (int off = 1; off < 64; off <<= 1) s += __shfl_xor(s, off, 64);
      float inv = 1.f / s;
      f32x4 g4 = { e[0] * inv, e[1] * inv, e[2] * inv, e[3] * inv };
      *(f32x4*)&gamma[(size_t)row * NKC + (lane << 2)] = g4;
      quant[(size_t)row * ND + lane] = mu[(size_t)bk * ND + lane];
    }
  }
}

// ---------- f64 refinement of flagged rows: exact argmin, overwrite quantized ----------
__global__ __launch_bounds__(256) void k_refine(const float* __restrict__ x,
                                                const float* __restrict__ w1, const float* __restrict__ b1,
                                                const float* __restrict__ w2, const float* __restrict__ b2,
                                                const float* __restrict__ mu,
                                                const int* __restrict__ flag_cnt,
                                                const int* __restrict__ flag_list,
                                                float* __restrict__ quant)
{
  __shared__ float  xs[8][DIN];     // 64000 B
  __shared__ double hs[8][NH];      // 32000 B
  __shared__ double zs[8][ND];      //  4096 B
  __shared__ double rd[256];
  __shared__ int    ri[256];
  __shared__ int    rows_s[8];

  const int tid = threadIdx.x;
  int cnt = *flag_cnt; if (cnt > FLAG_CAP) cnt = FLAG_CAP;
  const int base = blockIdx.x * 8;
  if (base >= cnt) return;
  const int nrows = (cnt - base < 8) ? (cnt - base) : 8;

  if (tid < 8) rows_s[tid] = (tid < nrows) ? flag_list[base + tid] : 0;
  __syncthreads();
  for (int r = 0; r < nrows; ++r) {
    const float* xr = x + (size_t)rows_s[r] * DIN;
    for (int c = tid; c < DIN; c += 256) xs[r][c] = xr[c];
  }
  __syncthreads();

  // h = relu(x @ w1^T + b1) in f64
  for (int hr = tid; hr < NH; hr += 256) {
    double acc[8];
#pragma unroll
    for (int r = 0; r < 8; ++r) acc[r] = (double)b1[hr];
    const float* wr = w1 + (size_t)hr * DIN;
    for (int k = 0; k < DIN; ++k) {
      double w = (double)wr[k];
#pragma unroll
      for (int r = 0; r < 8; ++r) acc[r] = fma(w, (double)xs[r][k], acc[r]);
    }
#pragma unroll
    for (int r = 0; r < 8; ++r) hs[r][hr] = acc[r] > 0.0 ? acc[r] : 0.0;
  }
  __syncthreads();

  // z = h @ w2^T + b2 in f64   (512 outputs = 8 rows x 64 dims)
  for (int idx = tid; idx < 8 * ND; idx += 256) {
    int r = idx >> 6, d = idx & 63;
    double a = (double)b2[d];
    const float* wr = w2 + (size_t)d * NH;
    for (int i = 0; i < NH; ++i) a = fma(hs[r][i], (double)wr[i], a);
    zs[r][d] = a;
  }
  __syncthreads();

  // distances + argmin per row (thread t <-> cluster t), first-index tie-break
  for (int r = 0; r < nrows; ++r) {
    double dist = 0.0;
    const float* mk = mu + (size_t)tid * ND;
#pragma unroll 8
    for (int d = 0; d < ND; ++d) {
      double t = zs[r][d] - (double)mk[d];
      dist = fma(t, t, dist);
    }
    rd[tid] = dist; ri[tid] = tid;
    __syncthreads();
    for (int s = 128; s > 0; s >>= 1) {
      if (tid < s) {
        if (rd[tid + s] < rd[tid] || (rd[tid + s] == rd[tid] && ri[tid + s] < ri[tid])) {
          rd[tid] = rd[tid + s]; ri[tid] = ri[tid + s];
        }
      }
      __syncthreads();
    }
    int best = ri[0];
    __syncthreads();
    if (tid < ND) quant[(size_t)rows_s[r] * ND + tid] = mu[(size_t)best * ND + tid];
    __syncthreads();
  }
}

// ---------- fc0: recon_z = [z | quantized] @ fc0_w^T + fc0_b  (f32, store bf16) ----------
__global__ __launch_bounds__(256) void k_fc0(const float* __restrict__ z, const float* __restrict__ quant,
                                             const float* __restrict__ W, const float* __restrict__ b,
                                             unsigned short* __restrict__ rz)
{
  __shared__ float Wt[2 * ND][ND];   // [128][64] transposed, 32 KB
  for (int i = threadIdx.x; i < ND * 2 * ND; i += 256) {
    int j = i >> 7;      // output index
    int ii = i & 127;    // input index
    Wt[ii][j] = W[i];
  }
  __syncthreads();
  const int lane = threadIdx.x & 63, wave = threadIdx.x >> 6;
  float bj = b[lane];
  for (int row = blockIdx.x * 4 + wave; row < NB; row += gridDim.x * 4) {
    float zv = z[(size_t)row * ND + lane];
    float qv = quant[(size_t)row * ND + lane];
    float acc = bj;
#pragma unroll 8
    for (int i = 0; i < ND; ++i) {
      acc = fmaf(__shfl(zv, i, 64), Wt[i][lane], acc);
      acc = fmaf(__shfl(qv, i, 64), Wt[ND + i][lane], acc);
    }
    rz[(size_t)row * ND + lane] = f2bf_rne(acc);
  }
}

// ---------- host ----------
extern "C" void kernel_launch(void* const* d_in, const int* in_sizes, int n_in,
                              void* d_out, int out_size, void* d_ws, size_t ws_size,
                              hipStream_t stream)
{
  const float* x      = (const float*)d_in[2];
  const float* mu     = (const float*)d_in[3];
  const float* enc_w1 = (const float*)d_in[4];
  const float* enc_b1 = (const float*)d_in[5];
  const float* enc_w2 = (const float*)d_in[6];
  const float* enc_b2 = (const float*)d_in[7];
  const float* fc0_w  = (const float*)d_in[8];
  const float* fc0_b  = (const float*)d_in[9];
  const float* dec_w1 = (const float*)d_in[10];
  const float* dec_b1 = (const float*)d_in[11];
  const float* dec_w2 = (const float*)d_in[12];
  const float* dec_b2 = (const float*)d_in[13];

  float* z_out  = (float*)d_out;
  float* q_out  = z_out + (size_t)NB * ND;
  float* g_out  = q_out + (size_t)NB * ND;
  float* rx_out = g_out + (size_t)NB * NKC;

  char* ws = (char*)d_ws;
  unsigned short* W1HI = (unsigned short*)ws; ws += (size_t)512 * 2048 * 2;
  unsigned short* W1LO = (unsigned short*)ws; ws += (size_t)512 * 2048 * 2;
  unsigned short* W2HI = (unsigned short*)ws; ws += (size_t)64 * 512 * 2;
  unsigned short* W2LO = (unsigned short*)ws; ws += (size_t)64 * 512 * 2;
  unsigned short* DW1  = (unsigned short*)ws; ws += (size_t)512 * 64 * 2;
  unsigned short* DW2  = (unsigned short*)ws; ws += (size_t)2048 * 512 * 2;
  unsigned short* HHI  = (unsigned short*)ws; ws += (size_t)NB * 512 * 2;
  unsigned short* HLO  = (unsigned short*)ws; ws += (size_t)NB * 512 * 2;
  unsigned short* H2   = (unsigned short*)ws; ws += (size_t)NB * 512 * 2;
  unsigned short* RZ   = (unsigned short*)ws; ws += (size_t)NB * ND * 2;
  int* FCNT = (int*)ws; ws += 256;                 // keep alignment
  int* FLST = (int*)ws; ws += (size_t)FLAG_CAP * 4;

  // weight conversion (+ zero padding)
  k_split_pad<<<1024, 256, 0, stream>>>(enc_w1, W1HI, W1LO, 500, 2000, 2048, 512 * 2048);
  k_split_pad<<<64, 256, 0, stream>>>(enc_w2, W2HI, W2LO, 64, 500, 512, 64 * 512);
  k_split_pad<<<64, 256, 0, stream>>>(dec_w1, DW1, nullptr, 500, 64, 64, 512 * 64);
  k_split_pad<<<1024, 256, 0, stream>>>(dec_w2, DW2, nullptr, 2000, 500, 512, 2048 * 512);
  k_zero<<<1, 64, 0, stream>>>(FCNT);

  // GEMM1: h = relu(x @ w1^T + b1), split 3-pass, A from f32 x
  dim3 g1(NB / 128, 4);
  k_gemm<128, 4, true, true, 1><<<g1, 256, 0, stream>>>(
      x, nullptr, W1HI, W1LO, enc_b1, 500, HHI, HLO, DIN, 2048, 2000, 512, 512);
  // GEMM2: z = h @ w2^T + b2, split 3-pass, f32 out
  dim3 g2(NB / 128, 1);
  k_gemm<64, 2, true, false, 0><<<g2, 256, 0, stream>>>(
      HHI, HLO, W2HI, W2LO, enc_b2, 64, z_out, nullptr, 512, 512, 512, 64, 64);
  // clustering (+ flip-risk flagging)
  k_cluster<<<256, 256, 0, stream>>>(z_out, mu, g_out, q_out, FCNT, FLST);
  // exact f64 argmin for flagged rows
  k_refine<<<FLAG_CAP / 8, 256, 0, stream>>>(x, enc_w1, enc_b1, enc_w2, enc_b2, mu,
                                             FCNT, FLST, q_out);
  // fc0
  k_fc0<<<256, 256, 0, stream>>>(z_out, q_out, fc0_w, fc0_b, RZ);
  // GEMM4: h2 = relu(recon_z @ dec_w1^T + b1), bf16
  dim3 g4(NB / 128, 4);
  k_gemm<128, 4, false, false, 2><<<g4, 256, 0, stream>>>(
      RZ, nullptr, DW1, nullptr, dec_b1, 500, H2, nullptr, 64, 64, 64, 512, 512);
  // GEMM5: recon_x = sigmoid(h2 @ dec_w2^T + b2), bf16, f32 masked store
  dim3 g5(NB / 128, 16);
  k_gemm<128, 4, false, false, 3><<<g5, 256, 0, stream>>>(
      H2, nullptr, DW2, nullptr, dec_b2, 2000, rx_out, nullptr, 512, 512, 512, 2000, 2000);
}

// Round 3
// 549.223 us; speedup vs baseline: 1.1865x; 1.1865x over previous
//
#include <hip/hip_runtime.h>
#include <stdint.h>
#include <math.h>

#define NB   16384   // batch
#define DIN  2000
#define NH   500     // hidden
#define ND   64      // dim
#define NKC  256     // clusters

#define FLAG_CAP 4096
#define GAP_THR  0.08f   // in sum-of-squares units (mean-units * 64); fast-path noise ~1e-3

typedef __attribute__((ext_vector_type(4))) float  f32x4;
typedef __attribute__((ext_vector_type(8))) short  s16x8;

// ---------- bf16 helpers ----------
__device__ __forceinline__ unsigned short f2bf_rne(float v) {
  unsigned int u = __float_as_uint(v);
  u += 0x7fffu + ((u >> 16) & 1u);
  return (unsigned short)(u >> 16);
}
// fast split: hi = truncate-to-bf16, lo = truncate(v - hi). total rel err <= 2^-16
__device__ __forceinline__ void split_rtz(float v, unsigned short &hi, unsigned short &lo) {
  unsigned int u = __float_as_uint(v);
  hi = (unsigned short)(u >> 16);
  float r = v - __uint_as_float(u & 0xffff0000u);
  lo = (unsigned short)(__float_as_uint(r) >> 16);
}

// ---------- weight convert (+zero-pad) ----------
__global__ void k_split_pad(const float* __restrict__ in, unsigned short* __restrict__ hi,
                            unsigned short* __restrict__ lo,
                            int R, int C, int Cp, int total) {
  int stride = gridDim.x * blockDim.x;
  for (int idx = blockIdx.x * blockDim.x + threadIdx.x; idx < total; idx += stride) {
    int r = idx / Cp, c = idx - r * Cp;
    float v = (r < R && c < C) ? in[(size_t)r * C + c] : 0.f;
    if (lo) {
      unsigned short h, l; split_rtz(v, h, l);
      hi[idx] = h; lo[idx] = l;
    } else {
      hi[idx] = f2bf_rne(v);
    }
  }
}

// ---------- GEMM: C[M,N] = A[M,K] * B[N,K]^T (+bias, epilogue) ----------
// EPI: 0 = f32 store (col<store_n), 1 = relu + split bf16 (out0=hi,out1=lo),
//      2 = relu + bf16 store, 3 = sigmoid + f32 store (col<store_n)
template<int BN, int WC, bool SPLIT, bool AF32, int EPI>
__global__ __launch_bounds__(256) void k_gemm(
    const void* __restrict__ Ahi_, const void* __restrict__ Alo_,
    const unsigned short* __restrict__ Bhi, const unsigned short* __restrict__ Blo,
    const float* __restrict__ bias, int bias_n,
    void* __restrict__ out0, void* __restrict__ out1,
    int ldA, int K, int Kreal, int out_ld, int store_n)
{
  constexpr int BM = 128, BK = 32, LDK = BK + 8, WR = 4;
  __shared__ unsigned short aHi[BM * LDK];
  __shared__ unsigned short aLo[SPLIT ? BM * LDK : 1];
  __shared__ unsigned short bHi[BN * LDK];
  __shared__ unsigned short bLo[SPLIT ? BN * LDK : 1];

  const int tid  = threadIdx.x;
  const int lane = tid & 63, wave = tid >> 6;
  const int wm = wave >> 1, wn = wave & 1;
  const int lr = lane & 15, lg = lane >> 4;
  const int m0 = blockIdx.x * BM, n0 = blockIdx.y * BN;

  f32x4 acc[WR][WC];
#pragma unroll
  for (int i = 0; i < WR; ++i)
#pragma unroll
    for (int j = 0; j < WC; ++j)
#pragma unroll
      for (int r = 0; r < 4; ++r) acc[i][j][r] = 0.f;

  for (int k0 = 0; k0 < K; k0 += BK) {
    // ---- stage A ----
    if constexpr (AF32) {
      const float* A = (const float*)Ahi_;
#pragma unroll
      for (int it = 0; it < (BM * BK / 8) / 256; ++it) {
        int c = it * 256 + tid;
        int row = c >> 2;
        int kc = (c & 3) << 3;
        float vb[8];
        if (k0 + kc < Kreal) {   // chunks of 8; Kreal % 8 == 0
          const float* src = A + (size_t)(m0 + row) * ldA + (k0 + kc);
          f32x4 v0 = *(const f32x4*)src;
          f32x4 v1 = *(const f32x4*)(src + 4);
          vb[0] = v0[0]; vb[1] = v0[1]; vb[2] = v0[2]; vb[3] = v0[3];
          vb[4] = v1[0]; vb[5] = v1[1]; vb[6] = v1[2]; vb[7] = v1[3];
        } else {
#pragma unroll
          for (int j = 0; j < 8; ++j) vb[j] = 0.f;
        }
        s16x8 h8, l8;
#pragma unroll
        for (int j = 0; j < 8; ++j) {
          unsigned short h, l; split_rtz(vb[j], h, l);
          h8[j] = (short)h; l8[j] = (short)l;
        }
        *(s16x8*)&aHi[row * LDK + kc] = h8;
        *(s16x8*)&aLo[row * LDK + kc] = l8;
      }
    } else {
      const unsigned short* A = (const unsigned short*)Ahi_;
#pragma unroll
      for (int it = 0; it < (BM * BK / 8) / 256; ++it) {
        int c = it * 256 + tid;
        int row = c >> 2, kc = (c & 3) << 3;
        *(s16x8*)&aHi[row * LDK + kc] = *(const s16x8*)(A + (size_t)(m0 + row) * ldA + k0 + kc);
        if constexpr (SPLIT) {
          const unsigned short* AL = (const unsigned short*)Alo_;
          *(s16x8*)&aLo[row * LDK + kc] = *(const s16x8*)(AL + (size_t)(m0 + row) * ldA + k0 + kc);
        }
      }
    }
    // ---- stage B (pre-padded buffers, row stride = K) ----
#pragma unroll
    for (int it = 0; it < (BN * BK / 8) / 256; ++it) {
      int c = it * 256 + tid;
      int row = c >> 2, kc = (c & 3) << 3;
      *(s16x8*)&bHi[row * LDK + kc] = *(const s16x8*)(Bhi + (size_t)(n0 + row) * K + k0 + kc);
      if constexpr (SPLIT)
        *(s16x8*)&bLo[row * LDK + kc] = *(const s16x8*)(Blo + (size_t)(n0 + row) * K + k0 + kc);
    }
    __syncthreads();

    // ---- fragments + MFMA ----
    s16x8 ah[WR], bh[WC];
#pragma unroll
    for (int i = 0; i < WR; ++i)
      ah[i] = *(const s16x8*)&aHi[(wm * (WR * 16) + i * 16 + lr) * LDK + lg * 8];
#pragma unroll
    for (int j = 0; j < WC; ++j)
      bh[j] = *(const s16x8*)&bHi[(wn * (WC * 16) + j * 16 + lr) * LDK + lg * 8];
    if constexpr (SPLIT) {
      s16x8 al[WR], bl[WC];
#pragma unroll
      for (int i = 0; i < WR; ++i)
        al[i] = *(const s16x8*)&aLo[(wm * (WR * 16) + i * 16 + lr) * LDK + lg * 8];
#pragma unroll
      for (int j = 0; j < WC; ++j)
        bl[j] = *(const s16x8*)&bLo[(wn * (WC * 16) + j * 16 + lr) * LDK + lg * 8];
#pragma unroll
      for (int i = 0; i < WR; ++i)
#pragma unroll
        for (int j = 0; j < WC; ++j) {
          acc[i][j] = __builtin_amdgcn_mfma_f32_16x16x32_bf16(ah[i], bh[j], acc[i][j], 0, 0, 0);
          acc[i][j] = __builtin_amdgcn_mfma_f32_16x16x32_bf16(ah[i], bl[j], acc[i][j], 0, 0, 0);
          acc[i][j] = __builtin_amdgcn_mfma_f32_16x16x32_bf16(al[i], bh[j], acc[i][j], 0, 0, 0);
        }
    } else {
#pragma unroll
      for (int i = 0; i < WR; ++i)
#pragma unroll
        for (int j = 0; j < WC; ++j)
          acc[i][j] = __builtin_amdgcn_mfma_f32_16x16x32_bf16(ah[i], bh[j], acc[i][j], 0, 0, 0);
    }
    __syncthreads();
  }

  // ---- epilogue: C/D layout col=lane&15, row=(lane>>4)*4+reg ----
#pragma unroll
  for (int i = 0; i < WR; ++i) {
    int grow = m0 + wm * (WR * 16) + i * 16 + lg * 4;
#pragma unroll
    for (int j = 0; j < WC; ++j) {
      int gcol = n0 + wn * (WC * 16) + j * 16 + lr;
      float bv = (gcol < bias_n) ? bias[gcol] : 0.f;
      f32x4 v = acc[i][j];
#pragma unroll
      for (int r = 0; r < 4; ++r) {
        float val = v[r] + bv;
        int rr = grow + r;
        if constexpr (EPI == 0) {
          if (gcol < store_n) ((float*)out0)[(size_t)rr * out_ld + gcol] = val;
        } else if constexpr (EPI == 1) {
          val = fmaxf(val, 0.f);
          unsigned short h, l; split_rtz(val, h, l);
          ((unsigned short*)out0)[(size_t)rr * out_ld + gcol] = h;
          ((unsigned short*)out1)[(size_t)rr * out_ld + gcol] = l;
        } else if constexpr (EPI == 2) {
          val = fmaxf(val, 0.f);
          ((unsigned short*)out0)[(size_t)rr * out_ld + gcol] = f2bf_rne(val);
        } else {
          val = 1.f / (1.f + expf(-val));
          if (gcol < store_n) ((float*)out0)[(size_t)rr * out_ld + gcol] = val;
        }
      }
    }
  }
}

// ---------- zero the flag counter ----------
__global__ void k_zero(int* __restrict__ p) { if (threadIdx.x == 0) *p = 0; }

// ---------- clustering: dists, softmax(gamma), argmin -> quantized, flag close rows ----------
__global__ __launch_bounds__(256) void k_cluster(const float* __restrict__ z,
                                                 const float* __restrict__ mu,
                                                 float* __restrict__ gamma,
                                                 float* __restrict__ quant,
                                                 int* __restrict__ flag_cnt,
                                                 int* __restrict__ flag_list)
{
  __shared__ float mu_t[ND][NKC];   // 64 x 256 f32 = 64 KB, transposed for conflict-free reads
  for (int i = threadIdx.x; i < NKC * ND; i += 256) {
    int k = i >> 6, d = i & 63;
    mu_t[d][k] = mu[i];
  }
  __syncthreads();
  const int lane = threadIdx.x & 63, wave = threadIdx.x >> 6;
  for (int r4 = blockIdx.x * 16 + wave * 4; r4 < NB; r4 += gridDim.x * 16) {
    float zr[4];
#pragma unroll
    for (int r = 0; r < 4; ++r) zr[r] = z[(size_t)(r4 + r) * ND + lane];
    float ds[4][4];
#pragma unroll
    for (int r = 0; r < 4; ++r)
#pragma unroll
      for (int g = 0; g < 4; ++g) ds[r][g] = 0.f;
    for (int d = 0; d < ND; ++d) {
      f32x4 m4 = *(const f32x4*)&mu_t[d][lane << 2];   // this lane's 4 centroids
#pragma unroll
      for (int r = 0; r < 4; ++r) {
        float zd = __shfl(zr[r], d, 64);
#pragma unroll
        for (int g = 0; g < 4; ++g) {
          float t = zd - m4[g];
          ds[r][g] = fmaf(t, t, ds[r][g]);
        }
      }
    }
#pragma unroll
    for (int r = 0; r < 4; ++r) {
      int row = r4 + r;
      float bd = ds[r][0]; int bk = (lane << 2);
#pragma unroll
      for (int g = 1; g < 4; ++g)
        if (ds[r][g] < bd) { bd = ds[r][g]; bk = (lane << 2) + g; }
      for (int off = 1; off < 64; off <<= 1) {
        float od = __shfl_xor(bd, off, 64);
        int   ok = __shfl_xor(bk, off, 64);
        if (od < bd || (od == bd && ok < bk)) { bd = od; bk = ok; }  // first-index tie-break
      }
      // second-best (excluding global best index) for the flip-risk flag
      float sb = 3.4e38f;
#pragma unroll
      for (int g = 0; g < 4; ++g) {
        int kk = (lane << 2) + g;
        if (kk != bk) sb = fminf(sb, ds[r][g]);
      }
      for (int off = 1; off < 64; off <<= 1) sb = fminf(sb, __shfl_xor(sb, off, 64));
      if (lane == 0 && (sb - bd) < GAP_THR) {
        int p = atomicAdd(flag_cnt, 1);
        if (p < FLAG_CAP) flag_list[p] = row;
      }
      const float cc = -5.f / 64.f;   // DELTA / dim (z_dist is a mean)
      float e[4], s = 0.f;
#pragma unroll
      for (int g = 0; g < 4; ++g) { e[g] = expf(cc * (ds[r][g] - bd)); s += e[g]; }
      for (int off = 1; off < 64; off <<= 1) s += __shfl_xor(s, off, 64);
      float inv = 1.f / s;
      f32x4 g4 = { e[0] * inv, e[1] * inv, e[2] * inv, e[3] * inv };
      *(f32x4*)&gamma[(size_t)row * NKC + (lane << 2)] = g4;
      quant[(size_t)row * ND + lane] = mu[(size_t)bk * ND + lane];
    }
  }
}

// ---------- f64 refinement of flagged rows: exact argmin, overwrite quantized ----------
// v2: 2 rows/block, 512 threads, coalesced f32x4 weight loads, lane-parallel k,
//     wave butterfly reduce. Same decision math (f64) and same flag set as v1.
__global__ __launch_bounds__(512) void k_refine(const float* __restrict__ x,
                                                const float* __restrict__ w1, const float* __restrict__ b1,
                                                const float* __restrict__ w2, const float* __restrict__ b2,
                                                const float* __restrict__ mu,
                                                const int* __restrict__ flag_cnt,
                                                const int* __restrict__ flag_list,
                                                float* __restrict__ quant)
{
  __shared__ __align__(16) float xs[2][DIN];   // 16000 B
  __shared__ double hs[2][NH];                 // 8000 B
  __shared__ double zs[2][ND];                 // 1024 B
  __shared__ double rd[256];
  __shared__ int    ri[256];
  __shared__ int    rows_s[2];

  int cnt = *flag_cnt; if (cnt > FLAG_CAP) cnt = FLAG_CAP;
  const int base = blockIdx.x * 2;
  if (base >= cnt) return;
  const int tid = threadIdx.x, lane = tid & 63, wave = tid >> 6;

  if (tid < 2) rows_s[tid] = flag_list[(base + tid < cnt) ? (base + tid) : base];
  __syncthreads();
  const int row0 = rows_s[0], row1 = rows_s[1];

  // stage x rows (coalesced)
  for (int c = tid; c < DIN; c += 512) {
    xs[0][c] = x[(size_t)row0 * DIN + c];
    xs[1][c] = x[(size_t)row1 * DIN + c];
  }
  __syncthreads();

  // ---- h = relu(x @ w1^T + b1) in f64; wave <-> h-row, lanes k-parallel ----
  for (int hr = wave; hr < NH; hr += 8) {
    const float* wr = w1 + (size_t)hr * DIN;
    double a0 = 0.0, a1 = 0.0;
    for (int c = lane; c < DIN / 4; c += 64) {          // 500 f32x4 chunks
      f32x4 w4 = *(const f32x4*)(wr + c * 4);
      f32x4 x0 = *(const f32x4*)(&xs[0][c * 4]);
      f32x4 x1 = *(const f32x4*)(&xs[1][c * 4]);
#pragma unroll
      for (int j = 0; j < 4; ++j) {
        a0 = fma((double)w4[j], (double)x0[j], a0);
        a1 = fma((double)w4[j], (double)x1[j], a1);
      }
    }
#pragma unroll
    for (int off = 32; off; off >>= 1) {
      a0 += __shfl_xor(a0, off, 64);
      a1 += __shfl_xor(a1, off, 64);
    }
    if (lane == 0) {
      double b = (double)b1[hr];
      double v0 = a0 + b, v1 = a1 + b;
      hs[0][hr] = v0 > 0.0 ? v0 : 0.0;
      hs[1][hr] = v1 > 0.0 ? v1 : 0.0;
    }
  }
  __syncthreads();

  // ---- z = h @ w2^T + b2 in f64; wave <-> z-dim, lanes i-parallel ----
  for (int d = wave; d < ND; d += 8) {
    const float* wr = w2 + (size_t)d * NH;
    double a0 = 0.0, a1 = 0.0;
    for (int i = lane; i < NH; i += 64) {
      double w = (double)wr[i];
      a0 = fma(hs[0][i], w, a0);
      a1 = fma(hs[1][i], w, a1);
    }
#pragma unroll
    for (int off = 32; off; off >>= 1) {
      a0 += __shfl_xor(a0, off, 64);
      a1 += __shfl_xor(a1, off, 64);
    }
    if (lane == 0) {
      double b = (double)b2[d];
      zs[0][d] = a0 + b;
      zs[1][d] = a1 + b;
    }
  }
  __syncthreads();

  // ---- distances + argmin per row (thread t <-> cluster t), first-index tie-break ----
  for (int r = 0; r < 2; ++r) {
    if (tid < NKC) {
      double dist = 0.0;
      const float* mk = mu + (size_t)tid * ND;
#pragma unroll 8
      for (int d = 0; d < ND; ++d) {
        double t = zs[r][d] - (double)mk[d];
        dist = fma(t, t, dist);
      }
      rd[tid] = dist; ri[tid] = tid;
    }
    __syncthreads();
    for (int s = 128; s > 0; s >>= 1) {
      if (tid < s) {
        if (rd[tid + s] < rd[tid] || (rd[tid + s] == rd[tid] && ri[tid + s] < ri[tid])) {
          rd[tid] = rd[tid + s]; ri[tid] = ri[tid + s];
        }
      }
      __syncthreads();
    }
    int best = ri[0];
    __syncthreads();
    if (tid < ND) quant[(size_t)rows_s[r] * ND + tid] = mu[(size_t)best * ND + tid];
    __syncthreads();
  }
}

// ---------- fc0: recon_z = [z | quantized] @ fc0_w^T + fc0_b  (f32, store bf16) ----------
__global__ __launch_bounds__(256) void k_fc0(const float* __restrict__ z, const float* __restrict__ quant,
                                             const float* __restrict__ W, const float* __restrict__ b,
                                             unsigned short* __restrict__ rz)
{
  __shared__ float Wt[2 * ND][ND];   // [128][64] transposed, 32 KB
  for (int i = threadIdx.x; i < ND * 2 * ND; i += 256) {
    int j = i >> 7;      // output index
    int ii = i & 127;    // input index
    Wt[ii][j] = W[i];
  }
  __syncthreads();
  const int lane = threadIdx.x & 63, wave = threadIdx.x >> 6;
  float bj = b[lane];
  for (int row = blockIdx.x * 4 + wave; row < NB; row += gridDim.x * 4) {
    float zv = z[(size_t)row * ND + lane];
    float qv = quant[(size_t)row * ND + lane];
    float acc = bj;
#pragma unroll 8
    for (int i = 0; i < ND; ++i) {
      acc = fmaf(__shfl(zv, i, 64), Wt[i][lane], acc);
      acc = fmaf(__shfl(qv, i, 64), Wt[ND + i][lane], acc);
    }
    rz[(size_t)row * ND + lane] = f2bf_rne(acc);
  }
}

// ---------- host ----------
extern "C" void kernel_launch(void* const* d_in, const int* in_sizes, int n_in,
                              void* d_out, int out_size, void* d_ws, size_t ws_size,
                              hipStream_t stream)
{
  const float* x      = (const float*)d_in[2];
  const float* mu     = (const float*)d_in[3];
  const float* enc_w1 = (const float*)d_in[4];
  const float* enc_b1 = (const float*)d_in[5];
  const float* enc_w2 = (const float*)d_in[6];
  const float* enc_b2 = (const float*)d_in[7];
  const float* fc0_w  = (const float*)d_in[8];
  const float* fc0_b  = (const float*)d_in[9];
  const float* dec_w1 = (const float*)d_in[10];
  const float* dec_b1 = (const float*)d_in[11];
  const float* dec_w2 = (const float*)d_in[12];
  const float* dec_b2 = (const float*)d_in[13];

  float* z_out  = (float*)d_out;
  float* q_out  = z_out + (size_t)NB * ND;
  float* g_out  = q_out + (size_t)NB * ND;
  float* rx_out = g_out + (size_t)NB * NKC;

  char* ws = (char*)d_ws;
  unsigned short* W1HI = (unsigned short*)ws; ws += (size_t)512 * 2048 * 2;
  unsigned short* W1LO = (unsigned short*)ws; ws += (size_t)512 * 2048 * 2;
  unsigned short* W2HI = (unsigned short*)ws; ws += (size_t)64 * 512 * 2;
  unsigned short* W2LO = (unsigned short*)ws; ws += (size_t)64 * 512 * 2;
  unsigned short* DW1  = (unsigned short*)ws; ws += (size_t)512 * 64 * 2;
  unsigned short* DW2  = (unsigned short*)ws; ws += (size_t)2048 * 512 * 2;
  unsigned short* HHI  = (unsigned short*)ws; ws += (size_t)NB * 512 * 2;
  unsigned short* HLO  = (unsigned short*)ws; ws += (size_t)NB * 512 * 2;
  unsigned short* H2   = (unsigned short*)ws; ws += (size_t)NB * 512 * 2;
  unsigned short* RZ   = (unsigned short*)ws; ws += (size_t)NB * ND * 2;
  int* FCNT = (int*)ws; ws += 256;                 // keep alignment
  int* FLST = (int*)ws; ws += (size_t)FLAG_CAP * 4;

  // weight conversion (+ zero padding)
  k_split_pad<<<1024, 256, 0, stream>>>(enc_w1, W1HI, W1LO, 500, 2000, 2048, 512 * 2048);
  k_split_pad<<<64, 256, 0, stream>>>(enc_w2, W2HI, W2LO, 64, 500, 512, 64 * 512);
  k_split_pad<<<64, 256, 0, stream>>>(dec_w1, DW1, nullptr, 500, 64, 64, 512 * 64);
  k_split_pad<<<1024, 256, 0, stream>>>(dec_w2, DW2, nullptr, 2000, 500, 512, 2048 * 512);
  k_zero<<<1, 64, 0, stream>>>(FCNT);

  // GEMM1: h = relu(x @ w1^T + b1), split 3-pass, A from f32 x
  dim3 g1(NB / 128, 4);
  k_gemm<128, 4, true, true, 1><<<g1, 256, 0, stream>>>(
      x, nullptr, W1HI, W1LO, enc_b1, 500, HHI, HLO, DIN, 2048, 2000, 512, 512);
  // GEMM2: z = h @ w2^T + b2, split 3-pass, f32 out
  dim3 g2(NB / 128, 1);
  k_gemm<64, 2, true, false, 0><<<g2, 256, 0, stream>>>(
      HHI, HLO, W2HI, W2LO, enc_b2, 64, z_out, nullptr, 512, 512, 512, 64, 64);
  // clustering (+ flip-risk flagging)
  k_cluster<<<256, 256, 0, stream>>>(z_out, mu, g_out, q_out, FCNT, FLST);
  // exact f64 argmin for flagged rows (2 rows/block)
  k_refine<<<FLAG_CAP / 2, 512, 0, stream>>>(x, enc_w1, enc_b1, enc_w2, enc_b2, mu,
                                             FCNT, FLST, q_out);
  // fc0
  k_fc0<<<256, 256, 0, stream>>>(z_out, q_out, fc0_w, fc0_b, RZ);
  // GEMM4: h2 = relu(recon_z @ dec_w1^T + b1), bf16
  dim3 g4(NB / 128, 4);
  k_gemm<128, 4, false, false, 2><<<g4, 256, 0, stream>>>(
      RZ, nullptr, DW1, nullptr, dec_b1, 500, H2, nullptr, 64, 64, 64, 512, 512);
  // GEMM5: recon_x = sigmoid(h2 @ dec_w2^T + b2), bf16, f32 masked store
  dim3 g5(NB / 128, 16);
  k_gemm<128, 4, false, false, 3><<<g5, 256, 0, stream>>>(
      H2, nullptr, DW2, nullptr, dec_b2, 2000, rx_out, nullptr, 512, 512, 512, 2000, 2000);
}

// Round 4
// 476.529 us; speedup vs baseline: 1.3675x; 1.1525x over previous
//
#include <hip/hip_runtime.h>
#include <stdint.h>
#include <math.h>

#define NB   16384   // batch
#define DIN  2000
#define NH   500     // hidden
#define ND   64      // dim
#define NKC  256     // clusters

#define FLAG_CAP 4096
#define GAP_THR  0.02f   // sum-of-squares units; fast-path noise ~1e-3 -> ~20x margin

typedef __attribute__((ext_vector_type(4))) float  f32x4;
typedef __attribute__((ext_vector_type(4))) double f64x4;
typedef __attribute__((ext_vector_type(8))) short  s16x8;

// ---------- bf16 helpers ----------
__device__ __forceinline__ unsigned short f2bf_rne(float v) {
  unsigned int u = __float_as_uint(v);
  u += 0x7fffu + ((u >> 16) & 1u);
  return (unsigned short)(u >> 16);
}
// fast split: hi = truncate-to-bf16, lo = truncate(v - hi). total rel err <= 2^-16
__device__ __forceinline__ void split_rtz(float v, unsigned short &hi, unsigned short &lo) {
  unsigned int u = __float_as_uint(v);
  hi = (unsigned short)(u >> 16);
  float r = v - __uint_as_float(u & 0xffff0000u);
  lo = (unsigned short)(__float_as_uint(r) >> 16);
}

// ---------- weight convert (+zero-pad) ----------
__global__ void k_split_pad(const float* __restrict__ in, unsigned short* __restrict__ hi,
                            unsigned short* __restrict__ lo,
                            int R, int C, int Cp, int total) {
  int stride = gridDim.x * blockDim.x;
  for (int idx = blockIdx.x * blockDim.x + threadIdx.x; idx < total; idx += stride) {
    int r = idx / Cp, c = idx - r * Cp;
    float v = (r < R && c < C) ? in[(size_t)r * C + c] : 0.f;
    if (lo) {
      unsigned short h, l; split_rtz(v, h, l);
      hi[idx] = h; lo[idx] = l;
    } else {
      hi[idx] = f2bf_rne(v);
    }
  }
}

// ---------- GEMM: C[M,N] = A[M,K] * B[N,K]^T (+bias, epilogue) ----------
// EPI: 0 = f32 store (col<store_n), 1 = relu + split bf16 (out0=hi,out1=lo),
//      2 = relu + bf16 store, 3 = sigmoid + f32 store (col<store_n)
template<int BN, int WC, bool SPLIT, bool AF32, int EPI>
__global__ __launch_bounds__(256) void k_gemm(
    const void* __restrict__ Ahi_, const void* __restrict__ Alo_,
    const unsigned short* __restrict__ Bhi, const unsigned short* __restrict__ Blo,
    const float* __restrict__ bias, int bias_n,
    void* __restrict__ out0, void* __restrict__ out1,
    int ldA, int K, int Kreal, int out_ld, int store_n)
{
  constexpr int BM = 128, BK = 32, LDK = BK + 8, WR = 4;
  __shared__ unsigned short aHi[BM * LDK];
  __shared__ unsigned short aLo[SPLIT ? BM * LDK : 1];
  __shared__ unsigned short bHi[BN * LDK];
  __shared__ unsigned short bLo[SPLIT ? BN * LDK : 1];

  const int tid  = threadIdx.x;
  const int lane = tid & 63, wave = tid >> 6;
  const int wm = wave >> 1, wn = wave & 1;
  const int lr = lane & 15, lg = lane >> 4;
  const int m0 = blockIdx.x * BM, n0 = blockIdx.y * BN;

  f32x4 acc[WR][WC];
#pragma unroll
  for (int i = 0; i < WR; ++i)
#pragma unroll
    for (int j = 0; j < WC; ++j)
#pragma unroll
      for (int r = 0; r < 4; ++r) acc[i][j][r] = 0.f;

  for (int k0 = 0; k0 < K; k0 += BK) {
    // ---- stage A ----
    if constexpr (AF32) {
      const float* A = (const float*)Ahi_;
#pragma unroll
      for (int it = 0; it < (BM * BK / 8) / 256; ++it) {
        int c = it * 256 + tid;
        int row = c >> 2;
        int kc = (c & 3) << 3;
        float vb[8];
        if (k0 + kc < Kreal) {   // chunks of 8; Kreal % 8 == 0
          const float* src = A + (size_t)(m0 + row) * ldA + (k0 + kc);
          f32x4 v0 = *(const f32x4*)src;
          f32x4 v1 = *(const f32x4*)(src + 4);
          vb[0] = v0[0]; vb[1] = v0[1]; vb[2] = v0[2]; vb[3] = v0[3];
          vb[4] = v1[0]; vb[5] = v1[1]; vb[6] = v1[2]; vb[7] = v1[3];
        } else {
#pragma unroll
          for (int j = 0; j < 8; ++j) vb[j] = 0.f;
        }
        s16x8 h8, l8;
#pragma unroll
        for (int j = 0; j < 8; ++j) {
          unsigned short h, l; split_rtz(vb[j], h, l);
          h8[j] = (short)h; l8[j] = (short)l;
        }
        *(s16x8*)&aHi[row * LDK + kc] = h8;
        *(s16x8*)&aLo[row * LDK + kc] = l8;
      }
    } else {
      const unsigned short* A = (const unsigned short*)Ahi_;
#pragma unroll
      for (int it = 0; it < (BM * BK / 8) / 256; ++it) {
        int c = it * 256 + tid;
        int row = c >> 2, kc = (c & 3) << 3;
        *(s16x8*)&aHi[row * LDK + kc] = *(const s16x8*)(A + (size_t)(m0 + row) * ldA + k0 + kc);
        if constexpr (SPLIT) {
          const unsigned short* AL = (const unsigned short*)Alo_;
          *(s16x8*)&aLo[row * LDK + kc] = *(const s16x8*)(AL + (size_t)(m0 + row) * ldA + k0 + kc);
        }
      }
    }
    // ---- stage B (pre-padded buffers, row stride = K) ----
#pragma unroll
    for (int it = 0; it < (BN * BK / 8) / 256; ++it) {
      int c = it * 256 + tid;
      int row = c >> 2, kc = (c & 3) << 3;
      *(s16x8*)&bHi[row * LDK + kc] = *(const s16x8*)(Bhi + (size_t)(n0 + row) * K + k0 + kc);
      if constexpr (SPLIT)
        *(s16x8*)&bLo[row * LDK + kc] = *(const s16x8*)(Blo + (size_t)(n0 + row) * K + k0 + kc);
    }
    __syncthreads();

    // ---- fragments + MFMA ----
    s16x8 ah[WR], bh[WC];
#pragma unroll
    for (int i = 0; i < WR; ++i)
      ah[i] = *(const s16x8*)&aHi[(wm * (WR * 16) + i * 16 + lr) * LDK + lg * 8];
#pragma unroll
    for (int j = 0; j < WC; ++j)
      bh[j] = *(const s16x8*)&bHi[(wn * (WC * 16) + j * 16 + lr) * LDK + lg * 8];
    if constexpr (SPLIT) {
      s16x8 al[WR], bl[WC];
#pragma unroll
      for (int i = 0; i < WR; ++i)
        al[i] = *(const s16x8*)&aLo[(wm * (WR * 16) + i * 16 + lr) * LDK + lg * 8];
#pragma unroll
      for (int j = 0; j < WC; ++j)
        bl[j] = *(const s16x8*)&bLo[(wn * (WC * 16) + j * 16 + lr) * LDK + lg * 8];
#pragma unroll
      for (int i = 0; i < WR; ++i)
#pragma unroll
        for (int j = 0; j < WC; ++j) {
          acc[i][j] = __builtin_amdgcn_mfma_f32_16x16x32_bf16(ah[i], bh[j], acc[i][j], 0, 0, 0);
          acc[i][j] = __builtin_amdgcn_mfma_f32_16x16x32_bf16(ah[i], bl[j], acc[i][j], 0, 0, 0);
          acc[i][j] = __builtin_amdgcn_mfma_f32_16x16x32_bf16(al[i], bh[j], acc[i][j], 0, 0, 0);
        }
    } else {
#pragma unroll
      for (int i = 0; i < WR; ++i)
#pragma unroll
        for (int j = 0; j < WC; ++j)
          acc[i][j] = __builtin_amdgcn_mfma_f32_16x16x32_bf16(ah[i], bh[j], acc[i][j], 0, 0, 0);
    }
    __syncthreads();
  }

  // ---- epilogue: C/D layout col=lane&15, row=(lane>>4)*4+reg ----
#pragma unroll
  for (int i = 0; i < WR; ++i) {
    int grow = m0 + wm * (WR * 16) + i * 16 + lg * 4;
#pragma unroll
    for (int j = 0; j < WC; ++j) {
      int gcol = n0 + wn * (WC * 16) + j * 16 + lr;
      float bv = (gcol < bias_n) ? bias[gcol] : 0.f;
      f32x4 v = acc[i][j];
#pragma unroll
      for (int r = 0; r < 4; ++r) {
        float val = v[r] + bv;
        int rr = grow + r;
        if constexpr (EPI == 0) {
          if (gcol < store_n) ((float*)out0)[(size_t)rr * out_ld + gcol] = val;
        } else if constexpr (EPI == 1) {
          val = fmaxf(val, 0.f);
          unsigned short h, l; split_rtz(val, h, l);
          ((unsigned short*)out0)[(size_t)rr * out_ld + gcol] = h;
          ((unsigned short*)out1)[(size_t)rr * out_ld + gcol] = l;
        } else if constexpr (EPI == 2) {
          val = fmaxf(val, 0.f);
          ((unsigned short*)out0)[(size_t)rr * out_ld + gcol] = f2bf_rne(val);
        } else {
          val = 1.f / (1.f + expf(-val));
          if (gcol < store_n) ((float*)out0)[(size_t)rr * out_ld + gcol] = val;
        }
      }
    }
  }
}

// ---------- zero the flag counter ----------
__global__ void k_zero(int* __restrict__ p) { if (threadIdx.x == 0) *p = 0; }

// ---------- clustering: dists, softmax(gamma), argmin -> quantized, flag close rows ----------
__global__ __launch_bounds__(256) void k_cluster(const float* __restrict__ z,
                                                 const float* __restrict__ mu,
                                                 float* __restrict__ gamma,
                                                 float* __restrict__ quant,
                                                 int* __restrict__ flag_cnt,
                                                 int* __restrict__ flag_list)
{
  __shared__ float mu_t[ND][NKC];   // 64 x 256 f32 = 64 KB, transposed for conflict-free reads
  for (int i = threadIdx.x; i < NKC * ND; i += 256) {
    int k = i >> 6, d = i & 63;
    mu_t[d][k] = mu[i];
  }
  __syncthreads();
  const int lane = threadIdx.x & 63, wave = threadIdx.x >> 6;
  for (int r4 = blockIdx.x * 16 + wave * 4; r4 < NB; r4 += gridDim.x * 16) {
    float zr[4];
#pragma unroll
    for (int r = 0; r < 4; ++r) zr[r] = z[(size_t)(r4 + r) * ND + lane];
    float ds[4][4];
#pragma unroll
    for (int r = 0; r < 4; ++r)
#pragma unroll
      for (int g = 0; g < 4; ++g) ds[r][g] = 0.f;
    for (int d = 0; d < ND; ++d) {
      f32x4 m4 = *(const f32x4*)&mu_t[d][lane << 2];   // this lane's 4 centroids
#pragma unroll
      for (int r = 0; r < 4; ++r) {
        float zd = __shfl(zr[r], d, 64);
#pragma unroll
        for (int g = 0; g < 4; ++g) {
          float t = zd - m4[g];
          ds[r][g] = fmaf(t, t, ds[r][g]);
        }
      }
    }
#pragma unroll
    for (int r = 0; r < 4; ++r) {
      int row = r4 + r;
      float bd = ds[r][0]; int bk = (lane << 2);
#pragma unroll
      for (int g = 1; g < 4; ++g)
        if (ds[r][g] < bd) { bd = ds[r][g]; bk = (lane << 2) + g; }
      for (int off = 1; off < 64; off <<= 1) {
        float od = __shfl_xor(bd, off, 64);
        int   ok = __shfl_xor(bk, off, 64);
        if (od < bd || (od == bd && ok < bk)) { bd = od; bk = ok; }  // first-index tie-break
      }
      // second-best (excluding global best index) for the flip-risk flag
      float sb = 3.4e38f;
#pragma unroll
      for (int g = 0; g < 4; ++g) {
        int kk = (lane << 2) + g;
        if (kk != bk) sb = fminf(sb, ds[r][g]);
      }
      for (int off = 1; off < 64; off <<= 1) sb = fminf(sb, __shfl_xor(sb, off, 64));
      if (lane == 0 && (sb - bd) < GAP_THR) {
        int p = atomicAdd(flag_cnt, 1);
        if (p < FLAG_CAP) flag_list[p] = row;
      }
      const float cc = -5.f / 64.f;   // DELTA / dim (z_dist is a mean)
      float e[4], s = 0.f;
#pragma unroll
      for (int g = 0; g < 4; ++g) { e[g] = expf(cc * (ds[r][g] - bd)); s += e[g]; }
      for (int off = 1; off < 64; off <<= 1) s += __shfl_xor(s, off, 64);
      float inv = 1.f / s;
      f32x4 g4 = { e[0] * inv, e[1] * inv, e[2] * inv, e[3] * inv };
      *(f32x4*)&gamma[(size_t)row * NKC + (lane << 2)] = g4;
      quant[(size_t)row * ND + lane] = mu[(size_t)bk * ND + lane];
    }
  }
}

// ---------- f64 refinement of flagged rows: exact argmin, overwrite quantized ----------
// v3: xs staged as f64 (no x-cvts in loop), 4 h-rows per wave-iter (interleaved
//     butterflies), coalesced w1 f32x4 loads. Same f64 decision math as v2.
__global__ __launch_bounds__(512) void k_refine(const float* __restrict__ x,
                                                const float* __restrict__ w1, const float* __restrict__ b1,
                                                const float* __restrict__ w2, const float* __restrict__ b2,
                                                const float* __restrict__ mu,
                                                const int* __restrict__ flag_cnt,
                                                const int* __restrict__ flag_list,
                                                float* __restrict__ quant)
{
  __shared__ __align__(16) double xs[2][DIN];   // 32000 B
  __shared__ double hs[2][NH];                  //  8000 B
  __shared__ double zs[2][ND];                  //  1024 B
  __shared__ double rd[256];
  __shared__ int    ri[256];
  __shared__ int    rows_s[2];

  int cnt = *flag_cnt; if (cnt > FLAG_CAP) cnt = FLAG_CAP;
  const int base = blockIdx.x * 2;
  if (base >= cnt) return;
  const int tid = threadIdx.x, lane = tid & 63, wave = tid >> 6;

  if (tid < 2) rows_s[tid] = flag_list[(base + tid < cnt) ? (base + tid) : base];
  __syncthreads();
  const int row0 = rows_s[0], row1 = rows_s[1];

  // stage x rows (coalesced), convert to f64 once
  for (int c = tid; c < DIN; c += 512) {
    xs[0][c] = (double)x[(size_t)row0 * DIN + c];
    xs[1][c] = (double)x[(size_t)row1 * DIN + c];
  }
  __syncthreads();

  // ---- h = relu(x @ w1^T + b1) in f64; 4 h-rows per wave-iter, lanes k-parallel ----
  for (int hr0 = wave * 4; hr0 < NH; hr0 += 32) {      // NH % 4 == 0
    double a[4][2];
#pragma unroll
    for (int r = 0; r < 4; ++r) { a[r][0] = 0.0; a[r][1] = 0.0; }
    for (int c = lane; c < DIN / 4; c += 64) {          // 500 f32x4 chunks
      f64x4 x0 = *(const f64x4*)(&xs[0][c * 4]);
      f64x4 x1 = *(const f64x4*)(&xs[1][c * 4]);
#pragma unroll
      for (int r = 0; r < 4; ++r) {
        f32x4 w4 = *(const f32x4*)(w1 + (size_t)(hr0 + r) * DIN + c * 4);
#pragma unroll
        for (int j = 0; j < 4; ++j) {
          double w = (double)w4[j];
          a[r][0] = fma(w, x0[j], a[r][0]);
          a[r][1] = fma(w, x1[j], a[r][1]);
        }
      }
    }
    // 4 independent butterfly pairs interleave -> latency amortized
#pragma unroll
    for (int off = 32; off; off >>= 1)
#pragma unroll
      for (int r = 0; r < 4; ++r) {
        a[r][0] += __shfl_xor(a[r][0], off, 64);
        a[r][1] += __shfl_xor(a[r][1], off, 64);
      }
    if (lane == 0) {
#pragma unroll
      for (int r = 0; r < 4; ++r) {
        double b = (double)b1[hr0 + r];
        double v0 = a[r][0] + b, v1 = a[r][1] + b;
        hs[0][hr0 + r] = v0 > 0.0 ? v0 : 0.0;
        hs[1][hr0 + r] = v1 > 0.0 ? v1 : 0.0;
      }
    }
  }
  __syncthreads();

  // ---- z = h @ w2^T + b2 in f64; wave <-> z-dim, lanes i-parallel ----
  for (int d = wave; d < ND; d += 8) {
    const float* wr = w2 + (size_t)d * NH;
    double a0 = 0.0, a1 = 0.0;
    for (int i = lane; i < NH; i += 64) {
      double w = (double)wr[i];
      a0 = fma(hs[0][i], w, a0);
      a1 = fma(hs[1][i], w, a1);
    }
#pragma unroll
    for (int off = 32; off; off >>= 1) {
      a0 += __shfl_xor(a0, off, 64);
      a1 += __shfl_xor(a1, off, 64);
    }
    if (lane == 0) {
      double b = (double)b2[d];
      zs[0][d] = a0 + b;
      zs[1][d] = a1 + b;
    }
  }
  __syncthreads();

  // ---- distances + argmin per row (thread t <-> cluster t), first-index tie-break ----
  for (int r = 0; r < 2; ++r) {
    if (tid < NKC) {
      double dist = 0.0;
      const float* mk = mu + (size_t)tid * ND;
#pragma unroll 8
      for (int d = 0; d < ND; ++d) {
        double t = zs[r][d] - (double)mk[d];
        dist = fma(t, t, dist);
      }
      rd[tid] = dist; ri[tid] = tid;
    }
    __syncthreads();
    for (int s = 128; s > 0; s >>= 1) {
      if (tid < s) {
        if (rd[tid + s] < rd[tid] || (rd[tid + s] == rd[tid] && ri[tid + s] < ri[tid])) {
          rd[tid] = rd[tid + s]; ri[tid] = ri[tid + s];
        }
      }
      __syncthreads();
    }
    int best = ri[0];
    __syncthreads();
    if (tid < ND) quant[(size_t)rows_s[r] * ND + tid] = mu[(size_t)best * ND + tid];
    __syncthreads();
  }
}

// ---------- fc0: recon_z = [z | quantized] @ fc0_w^T + fc0_b  (f32, store bf16) ----------
__global__ __launch_bounds__(256) void k_fc0(const float* __restrict__ z, const float* __restrict__ quant,
                                             const float* __restrict__ W, const float* __restrict__ b,
                                             unsigned short* __restrict__ rz)
{
  __shared__ float Wt[2 * ND][ND];   // [128][64] transposed, 32 KB
  for (int i = threadIdx.x; i < ND * 2 * ND; i += 256) {
    int j = i >> 7;      // output index
    int ii = i & 127;    // input index
    Wt[ii][j] = W[i];
  }
  __syncthreads();
  const int lane = threadIdx.x & 63, wave = threadIdx.x >> 6;
  float bj = b[lane];
  for (int row = blockIdx.x * 4 + wave; row < NB; row += gridDim.x * 4) {
    float zv = z[(size_t)row * ND + lane];
    float qv = quant[(size_t)row * ND + lane];
    float acc = bj;
#pragma unroll 8
    for (int i = 0; i < ND; ++i) {
      acc = fmaf(__shfl(zv, i, 64), Wt[i][lane], acc);
      acc = fmaf(__shfl(qv, i, 64), Wt[ND + i][lane], acc);
    }
    rz[(size_t)row * ND + lane] = f2bf_rne(acc);
  }
}

// ---------- host ----------
extern "C" void kernel_launch(void* const* d_in, const int* in_sizes, int n_in,
                              void* d_out, int out_size, void* d_ws, size_t ws_size,
                              hipStream_t stream)
{
  const float* x      = (const float*)d_in[2];
  const float* mu     = (const float*)d_in[3];
  const float* enc_w1 = (const float*)d_in[4];
  const float* enc_b1 = (const float*)d_in[5];
  const float* enc_w2 = (const float*)d_in[6];
  const float* enc_b2 = (const float*)d_in[7];
  const float* fc0_w  = (const float*)d_in[8];
  const float* fc0_b  = (const float*)d_in[9];
  const float* dec_w1 = (const float*)d_in[10];
  const float* dec_b1 = (const float*)d_in[11];
  const float* dec_w2 = (const float*)d_in[12];
  const float* dec_b2 = (const float*)d_in[13];

  float* z_out  = (float*)d_out;
  float* q_out  = z_out + (size_t)NB * ND;
  float* g_out  = q_out + (size_t)NB * ND;
  float* rx_out = g_out + (size_t)NB * NKC;

  char* ws = (char*)d_ws;
  unsigned short* W1HI = (unsigned short*)ws; ws += (size_t)512 * 2048 * 2;
  unsigned short* W1LO = (unsigned short*)ws; ws += (size_t)512 * 2048 * 2;
  unsigned short* W2HI = (unsigned short*)ws; ws += (size_t)64 * 512 * 2;
  unsigned short* W2LO = (unsigned short*)ws; ws += (size_t)64 * 512 * 2;
  unsigned short* DW1  = (unsigned short*)ws; ws += (size_t)512 * 64 * 2;
  unsigned short* DW2  = (unsigned short*)ws; ws += (size_t)2048 * 512 * 2;
  unsigned short* HHI  = (unsigned short*)ws; ws += (size_t)NB * 512 * 2;
  unsigned short* HLO  = (unsigned short*)ws; ws += (size_t)NB * 512 * 2;
  unsigned short* H2   = (unsigned short*)ws; ws += (size_t)NB * 512 * 2;
  unsigned short* RZ   = (unsigned short*)ws; ws += (size_t)NB * ND * 2;
  int* FCNT = (int*)ws; ws += 256;                 // keep alignment
  int* FLST = (int*)ws; ws += (size_t)FLAG_CAP * 4;

  // weight conversion (+ zero padding)
  k_split_pad<<<1024, 256, 0, stream>>>(enc_w1, W1HI, W1LO, 500, 2000, 2048, 512 * 2048);
  k_split_pad<<<64, 256, 0, stream>>>(enc_w2, W2HI, W2LO, 64, 500, 512, 64 * 512);
  k_split_pad<<<64, 256, 0, stream>>>(dec_w1, DW1, nullptr, 500, 64, 64, 512 * 64);
  k_split_pad<<<1024, 256, 0, stream>>>(dec_w2, DW2, nullptr, 2000, 500, 512, 2048 * 512);
  k_zero<<<1, 64, 0, stream>>>(FCNT);

  // GEMM1: h = relu(x @ w1^T + b1), split 3-pass, A from f32 x
  dim3 g1(NB / 128, 4);
  k_gemm<128, 4, true, true, 1><<<g1, 256, 0, stream>>>(
      x, nullptr, W1HI, W1LO, enc_b1, 500, HHI, HLO, DIN, 2048, 2000, 512, 512);
  // GEMM2: z = h @ w2^T + b2, split 3-pass, f32 out
  dim3 g2(NB / 128, 1);
  k_gemm<64, 2, true, false, 0><<<g2, 256, 0, stream>>>(
      HHI, HLO, W2HI, W2LO, enc_b2, 64, z_out, nullptr, 512, 512, 512, 64, 64);
  // clustering (+ flip-risk flagging)
  k_cluster<<<256, 256, 0, stream>>>(z_out, mu, g_out, q_out, FCNT, FLST);
  // exact f64 argmin for flagged rows (2 rows/block)
  k_refine<<<FLAG_CAP / 2, 512, 0, stream>>>(x, enc_w1, enc_b1, enc_w2, enc_b2, mu,
                                             FCNT, FLST, q_out);
  // fc0
  k_fc0<<<256, 256, 0, stream>>>(z_out, q_out, fc0_w, fc0_b, RZ);
  // GEMM4: h2 = relu(recon_z @ dec_w1^T + b1), bf16
  dim3 g4(NB / 128, 4);
  k_gemm<128, 4, false, false, 2><<<g4, 256, 0, stream>>>(
      RZ, nullptr, DW1, nullptr, dec_b1, 500, H2, nullptr, 64, 64, 64, 512, 512);
  // GEMM5: recon_x = sigmoid(h2 @ dec_w2^T + b2), bf16, f32 masked store
  dim3 g5(NB / 128, 16);
  k_gemm<128, 4, false, false, 3><<<g5, 256, 0, stream>>>(
      H2, nullptr, DW2, nullptr, dec_b2, 2000, rx_out, nullptr, 512, 512, 512, 2000, 2000);
}